// Round 1
// baseline (575.043 us; speedup 1.0000x reference)
//
#include <hip/hip_runtime.h>

#define T_TOKENS 8192
#define MDIM 1024
#define NEXP 8
#define DFF_DIM 4096
#define CAP 1280

typedef __attribute__((ext_vector_type(8))) short short8;
typedef __attribute__((ext_vector_type(4))) float f32x4;

__device__ inline unsigned short f2bf(float f) {
  unsigned u = __float_as_uint(f);
  u = u + 0x7fffu + ((u >> 16) & 1u);
  return (unsigned short)(u >> 16);
}

// async global->LDS DMA, 16B per lane. LDS dst must be wave-uniform base;
// lane i's data lands at base + i*16B (guide §5, m97/m104).
__device__ __forceinline__ void async_ld16(const void* g, void* l) {
  __builtin_amdgcn_global_load_lds(
      (__attribute__((address_space(1))) void*)const_cast<void*>(g),
      (__attribute__((address_space(3))) void*)l, 16, 0, 0);
}

// ---------------- gating: logits in fp64, softmax top-1 ----------------
__global__ __launch_bounds__(64) void gate_kernel(const float* __restrict__ x,
    const float* __restrict__ wg, int* __restrict__ eidx, float* __restrict__ gate)
{
  const int t = blockIdx.x;
  const int lane = threadIdx.x;
  const float* xr = x + (size_t)t * MDIM;
  double acc[NEXP];
  #pragma unroll
  for (int e = 0; e < NEXP; ++e) acc[e] = 0.0;
  for (int m = lane; m < MDIM; m += 64) {
    double xv = (double)xr[m];
    const float* wr = wg + (size_t)m * NEXP;
    #pragma unroll
    for (int e = 0; e < NEXP; ++e) acc[e] += xv * (double)wr[e];
  }
  #pragma unroll
  for (int off = 32; off > 0; off >>= 1) {
    #pragma unroll
    for (int e = 0; e < NEXP; ++e) acc[e] += __shfl_down(acc[e], off);
  }
  if (lane == 0) {
    double mx = acc[0]; int idx = 0;
    #pragma unroll
    for (int e = 1; e < NEXP; ++e) if (acc[e] > mx) { mx = acc[e]; idx = e; }
    double s = 0.0;
    #pragma unroll
    for (int e = 0; e < NEXP; ++e) s += exp(acc[e] - mx);
    eidx[t] = idx;
    gate[t] = (float)(1.0 / s);   // softmax prob of argmax expert
  }
}

// ---------------- order-preserving capacity scan (single block) ----------------
__global__ __launch_bounds__(1024) void scan_kernel(const int* __restrict__ eidx,
    int* __restrict__ slot_token, int* __restrict__ filled)
{
  __shared__ int hist[16][NEXP];
  __shared__ int wpre[16][NEXP];
  __shared__ int rtot[NEXP];
  __shared__ int base[NEXP];
  const int tid = threadIdx.x;
  const int w = tid >> 6, lane = tid & 63;
  for (int i = tid; i < NEXP * CAP; i += 1024) slot_token[i] = -1;
  if (tid < NEXP) base[tid] = 0;
  __syncthreads();
  const unsigned long long lt = (1ull << lane) - 1ull;
  for (int r = 0; r < T_TOKENS / 1024; ++r) {
    const int t = r * 1024 + tid;
    const int e = eidx[t];
    unsigned long long bal[NEXP];
    #pragma unroll
    for (int ee = 0; ee < NEXP; ++ee) bal[ee] = __ballot(e == ee);
    const int rank = __popcll(bal[e] & lt);
    if (lane < NEXP) hist[w][lane] = __popcll(bal[lane]);
    __syncthreads();
    if (tid < 16 * NEXP) {
      int ww = tid >> 3, ee = tid & 7, s = 0;
      for (int j = 0; j < ww; ++j) s += hist[j][ee];
      wpre[ww][ee] = s;
    }
    if (tid < NEXP) {
      int s = 0;
      for (int j = 0; j < 16; ++j) s += hist[j][tid];
      rtot[tid] = s;
    }
    __syncthreads();
    const int pos = base[e] + wpre[w][e] + rank;
    if (pos < CAP) slot_token[e * CAP + pos] = t;
    __syncthreads();
    if (tid < NEXP) base[tid] += rtot[tid];
    __syncthreads();
  }
  if (tid < NEXP) filled[tid] = (base[tid] < CAP) ? base[tid] : CAP;
}

// ---------------- dispatch: gather kept tokens into [E,C,M] bf16 ----------------
__global__ __launch_bounds__(256) void dispatch_kernel(const float* __restrict__ x,
    const int* __restrict__ slot_token, unsigned short* __restrict__ Abuf)
{
  const int row = blockIdx.x;
  const int tid = threadIdx.x;
  const int t = slot_token[row];
  unsigned short* dst = Abuf + (size_t)row * MDIM + tid * 4;
  if (t < 0) {
    ushort4 z; z.x = 0; z.y = 0; z.z = 0; z.w = 0;
    *(ushort4*)dst = z;
  } else {
    const float4 v = *(const float4*)(x + (size_t)t * MDIM + tid * 4);
    ushort4 h;
    h.x = f2bf(v.x); h.y = f2bf(v.y); h.z = f2bf(v.z); h.w = f2bf(v.w);
    *(ushort4*)dst = h;
  }
}

// ------------- weight transpose + fp32->bf16: src [R][Cc] -> dst [Cc][R] -------------
template<int R, int Cc>
__global__ __launch_bounds__(256) void transpose_cvt_kernel(
    const float* __restrict__ src, unsigned short* __restrict__ dst)
{
  __shared__ unsigned short tile[64][66];   // +2 pad: write-phase column reads ~2-way
  const int e = blockIdx.z;
  const int r0 = blockIdx.y * 64;
  const int c0 = blockIdx.x * 64;
  const int t = threadIdx.x;
  const float* S = src + (size_t)e * R * Cc;
  unsigned short* D = dst + (size_t)e * R * Cc;
  const int tr = t >> 4;         // 0..15
  const int tc = (t & 15) * 4;   // 0..60
  #pragma unroll
  for (int i = 0; i < 4; ++i) {
    const int row = i * 16 + tr;
    const float4 v = *(const float4*)(S + (size_t)(r0 + row) * Cc + c0 + tc);
    tile[row][tc + 0] = f2bf(v.x);
    tile[row][tc + 1] = f2bf(v.y);
    tile[row][tc + 2] = f2bf(v.z);
    tile[row][tc + 3] = f2bf(v.w);
  }
  __syncthreads();
  #pragma unroll
  for (int i = 0; i < 4; ++i) {
    const int crow = i * 16 + tr;   // src col index
    ushort4 o;
    o.x = tile[tc + 0][crow];
    o.y = tile[tc + 1][crow];
    o.z = tile[tc + 2][crow];
    o.w = tile[tc + 3][crow];
    *(ushort4*)(D + (size_t)(c0 + crow) * R + r0 + tc) = o;
  }
}

// =====================================================================
// GEMM1: H = relu(A @ W1T^T + b1), 256x256 tile, BK=32, 8 waves (2x4),
// 4 LDS buffers (128 KiB), counted-vmcnt pipeline (never vmcnt(0) in loop),
// T2 chunk swizzle, T5 setprio, T1 bijective XCD swizzle.
//
// Pipeline proof sketch: tile t computes from buf[t&3]; during tile t we
// issue stages for tile t+3 into buf[(t+3)&3], whose previous content
// (tile t-1) was fully read before tile t's first barrier -> no WAR race.
// At tile t's end, issued tiles = 0..t+3 (4 loads/thread each); vmcnt(8)
// leaves tiles t+2,t+3 (8 loads) in flight and guarantees tile t+1's 4
// loads have landed; the following s_barrier makes that guarantee
// cross-wave. -> tile t+1's ds_reads are safe.
//
// T2 swizzle: LDS tile is [256 rows][4 x 16B chunks] (row = 64 B). Stored
// chunk c of row r holds global chunk c ^ ((r>>1)&3) (involution). Reads
// use chunk (lane>>4) ^ (((lane&15)>>1)&3): a quarter-wave's 16 lanes then
// spread over all 8 (row-parity, chunk) bank groups, 2 lanes each = free
// (m136: 2-way is 1.02x). Staging keeps LDS linear and pre-swizzles the
// per-lane GLOBAL source chunk (rule 21: both-sides-or-neither).
// =====================================================================
__global__ __launch_bounds__(512, 2) void gemm1_256(
    const unsigned short* __restrict__ A,   // [E][CAP][K] bf16
    const unsigned short* __restrict__ Bt,  // [E][N][K] bf16 (pre-transposed W1)
    const float* __restrict__ bias,         // [E][N]
    unsigned short* __restrict__ H,         // [E][CAP][N] bf16
    const int* __restrict__ filled)
{
  constexpr int N = DFF_DIM;   // 4096
  constexpr int K = MDIM;      // 1024
  constexpr int NT = K / 32;   // 32 k-tiles
  static_assert(CAP % 256 == 0, "row blocking");

  // T1: 640 blocks, 640%8==0 -> simple bijective swizzle; 80 blocks/XCD =
  // exactly one expert per XCD (its B panel gets the XCD's private L2).
  const int id = blockIdx.x;
  const int wk = (id & 7) * 80 + (id >> 3);
  const int e = wk / 80;
  const int rem = wk % 80;
  const int rowbase = (rem / 16) * 256;
  const int colbase = (rem % 16) * 256;
  if (rowbase >= filled[e]) return;   // block-uniform early exit (before barriers)

  // 4 buffers x (A 16KB + B 16KB) = 128 KiB
  __shared__ unsigned short lds[4 * 16384];

  const int tid = threadIdx.x;
  const int lane = tid & 63;
  const int wid = tid >> 6;         // 0..7
  const int wm = wid >> 2;          // 0..1 : 128-row half
  const int wn = wid & 3;           // 0..3 : 64-col slice
  const int qm = lane & 15;
  const int qr = lane >> 4;         // 0..3
  const int swc  = qr ^ ((qm >> 1) & 3);                 // read-side chunk
  const int srcc = (lane & 3) ^ ((lane >> 3) & 3);       // stage-side source chunk

  const unsigned short* Ab = A + ((size_t)e * CAP + rowbase) * K;
  const unsigned short* Bb = Bt + ((size_t)e * N + colbase) * K;

  // staging: unit = 128 rows x 32 k = 8 KB = 512 threads x 16 B (1 load/thread)
  const int srow = wid * 16 + (lane >> 2);               // 0..127 within unit
  const unsigned short* aU0 = Ab + (size_t)srow * K + srcc * 8;
  const unsigned short* aU1 = Ab + (size_t)(srow + 128) * K + srcc * 8;
  const unsigned short* bU0 = Bb + (size_t)srow * K + srcc * 8;
  const unsigned short* bU1 = Bb + (size_t)(srow + 128) * K + srcc * 8;

  f32x4 acc[8][4];
  #pragma unroll
  for (int i = 0; i < 8; ++i)
    #pragma unroll
    for (int j = 0; j < 4; ++j)
      #pragma unroll
      for (int r = 0; r < 4; ++r) acc[i][j][r] = 0.0f;

  // wave-uniform LDS dst bases (lane offset is implicit lane*16B in HW)
  #define STAGE_A(tt, bb) do { \
    const int k0_ = (tt) * 32; \
    unsigned short* l_ = lds + (bb) * 16384 + wid * 512; \
    async_ld16(aU0 + k0_, l_); \
    async_ld16(aU1 + k0_, l_ + 4096); \
  } while (0)
  #define STAGE_B(tt, bb) do { \
    const int k0_ = (tt) * 32; \
    unsigned short* l_ = lds + (bb) * 16384 + 8192 + wid * 512; \
    async_ld16(bU0 + k0_, l_); \
    async_ld16(bU1 + k0_, l_ + 4096); \
  } while (0)

  // prologue: tiles 0,1,2 -> bufs 0,1,2 (12 loads/thread)
  STAGE_A(0, 0); STAGE_B(0, 0);
  STAGE_A(1, 1); STAGE_B(1, 1);
  STAGE_A(2, 2); STAGE_B(2, 2);
  asm volatile("s_waitcnt vmcnt(8)" ::: "memory");   // tile 0 landed
  __builtin_amdgcn_s_barrier();

  for (int t = 0; t < NT; ++t) {
    const int buf = t & 3;
    const int pbuf = (t + 3) & 3;
    int ts = t + 3; if (ts >= NT) ts -= NT;   // wrapped source keeps vmcnt
                                              // arithmetic uniform; target buf
                                              // is dead for tiles >= NT.
    const unsigned short* Ap = lds + buf * 16384;
    const unsigned short* Bp = Ap + 8192;
    short8 af[4], bfr[4];

    // ---- phase 0: C rows 0..63 of the wave's half ----
    #pragma unroll
    for (int i = 0; i < 4; ++i)
      af[i] = *(const short8*)(Ap + (wm * 128 + i * 16 + qm) * 32 + swc * 8);
    #pragma unroll
    for (int j = 0; j < 4; ++j)
      bfr[j] = *(const short8*)(Bp + (wn * 64 + j * 16 + qm) * 32 + swc * 8);
    STAGE_A(ts, pbuf);
    __builtin_amdgcn_s_barrier();
    asm volatile("s_waitcnt lgkmcnt(0)" ::: "memory");
    __builtin_amdgcn_sched_barrier(0);
    __builtin_amdgcn_s_setprio(1);
    #pragma unroll
    for (int i = 0; i < 4; ++i)
      #pragma unroll
      for (int j = 0; j < 4; ++j)
        acc[i][j] = __builtin_amdgcn_mfma_f32_16x16x32_bf16(af[i], bfr[j], acc[i][j], 0, 0, 0);
    __builtin_amdgcn_s_setprio(0);
    __builtin_amdgcn_s_barrier();

    // ---- phase 1: C rows 64..127 (reuse bfr, re-read af) ----
    #pragma unroll
    for (int i = 0; i < 4; ++i)
      af[i] = *(const short8*)(Ap + (wm * 128 + (i + 4) * 16 + qm) * 32 + swc * 8);
    STAGE_B(ts, pbuf);
    __builtin_amdgcn_s_barrier();
    asm volatile("s_waitcnt lgkmcnt(0)" ::: "memory");
    __builtin_amdgcn_sched_barrier(0);
    __builtin_amdgcn_s_setprio(1);
    #pragma unroll
    for (int i = 0; i < 4; ++i)
      #pragma unroll
      for (int j = 0; j < 4; ++j)
        acc[4 + i][j] = __builtin_amdgcn_mfma_f32_16x16x32_bf16(af[i], bfr[j], acc[4 + i][j], 0, 0, 0);
    __builtin_amdgcn_s_setprio(0);
    asm volatile("s_waitcnt vmcnt(8)" ::: "memory");   // tile t+1 guaranteed
    __builtin_amdgcn_s_barrier();
  }
  #undef STAGE_A
  #undef STAGE_B

  // drain outstanding DMA before LDS dealloc / epilogue
  asm volatile("s_waitcnt vmcnt(0)" ::: "memory");

  float bcol[4];
  #pragma unroll
  for (int j = 0; j < 4; ++j)
    bcol[j] = bias[(size_t)e * N + colbase + wn * 64 + j * 16 + qm];

  #pragma unroll
  for (int i = 0; i < 8; ++i) {
    #pragma unroll
    for (int r = 0; r < 4; ++r) {
      const int row = rowbase + wm * 128 + i * 16 + qr * 4 + r;
      unsigned short* orow = H + ((size_t)e * CAP + row) * N + colbase;
      #pragma unroll
      for (int j = 0; j < 4; ++j) {
        float v = acc[i][j][r] + bcol[j];
        v = v > 0.0f ? v : 0.0f;
        orow[wn * 64 + j * 16 + qm] = f2bf(v);
      }
    }
  }
}

// ---------------- GEMM2: out[token] = gate*(H @ W2T^T + b2) ----------------
// proven m97-style 128x128 kernel (kept: N=1024 makes 256^2 grids too small),
// + T1 bijective XCD swizzle (80 blocks/XCD = one expert per XCD L2).
__global__ __launch_bounds__(256) void gemm2_kernel(
    const unsigned short* __restrict__ A, const unsigned short* __restrict__ Bt,
    const float* __restrict__ bias, float* __restrict__ Op,
    const int* __restrict__ slot_token, const float* __restrict__ gate,
    const int* __restrict__ filled)
{
  constexpr int N = MDIM;      // 1024
  constexpr int K = DFF_DIM;   // 4096
  const int id = blockIdx.x;   // 640 blocks: 8 bx * 10 by * 8 e
  const int wk = (id & 7) * 80 + (id >> 3);
  const int e = wk / 80;
  const int rem = wk % 80;
  const int colbase = (rem / 10) * 128;
  const int rowbase = (rem % 10) * 128;   // by fastest: B col-panel L2-resident
  if (rowbase >= filled[e]) return;

  __shared__ unsigned short As[128 * 32];
  __shared__ unsigned short Bs[128 * 32];

  const int tid = threadIdx.x;
  const int lane = tid & 63;
  const int wid = tid >> 6;
  const int wm = (wid >> 1) * 64, wn = (wid & 1) * 64;
  const int qm = lane & 15, qk = (lane >> 4) * 8, qr = lane >> 4;

  const unsigned short* Ab = A + ((size_t)e * CAP + rowbase) * K;
  const unsigned short* Bb = Bt + ((size_t)e * N + colbase) * K;

  const int ldr = wid * 16 + (lane >> 2);
  const int ldk = (lane & 3) * 8;
  const unsigned short* ag = Ab + (size_t)ldr * K + ldk;
  const unsigned short* bg = Bb + (size_t)ldr * K + ldk;
  unsigned short* asw = As + wid * 512;
  unsigned short* bsw = Bs + wid * 512;

  f32x4 acc[4][4];
  #pragma unroll
  for (int i = 0; i < 4; ++i)
    #pragma unroll
    for (int j = 0; j < 4; ++j)
      #pragma unroll
      for (int r = 0; r < 4; ++r) acc[i][j][r] = 0.0f;

  for (int k0 = 0; k0 < K; k0 += 32) {
    __syncthreads();
    async_ld16(ag + k0,                  asw);
    async_ld16(ag + (size_t)64 * K + k0, asw + 2048);
    async_ld16(bg + k0,                  bsw);
    async_ld16(bg + (size_t)64 * K + k0, bsw + 2048);
    __syncthreads();
    short8 af[4], bfr[4];
    #pragma unroll
    for (int i = 0; i < 4; ++i) af[i] = *(const short8*)(As + (wm + i * 16 + qm) * 32 + qk);
    #pragma unroll
    for (int j = 0; j < 4; ++j) bfr[j] = *(const short8*)(Bs + (wn + j * 16 + qm) * 32 + qk);
    #pragma unroll
    for (int i = 0; i < 4; ++i)
      #pragma unroll
      for (int j = 0; j < 4; ++j)
        acc[i][j] = __builtin_amdgcn_mfma_f32_16x16x32_bf16(af[i], bfr[j], acc[i][j], 0, 0, 0);
  }

  float bcol[4];
  #pragma unroll
  for (int j = 0; j < 4; ++j)
    bcol[j] = bias[(size_t)e * N + colbase + wn + j * 16 + qm];

  #pragma unroll
  for (int i = 0; i < 4; ++i) {
    #pragma unroll
    for (int r = 0; r < 4; ++r) {
      const int row = rowbase + wm + i * 16 + qr * 4 + r;
      const int t = slot_token[e * CAP + row];
      if (t >= 0) {
        const float g = gate[t];
        float* orow = Op + (size_t)t * MDIM + colbase;
        #pragma unroll
        for (int j = 0; j < 4; ++j)
          orow[wn + j * 16 + qm] = g * (acc[i][j][r] + bcol[j]);
      }
    }
  }
}

extern "C" void kernel_launch(void* const* d_in, const int* in_sizes, int n_in,
                              void* d_out, int out_size, void* d_ws, size_t ws_size,
                              hipStream_t stream) {
  const float* x  = (const float*)d_in[0];
  const float* wg = (const float*)d_in[1];
  const float* w1 = (const float*)d_in[2];
  const float* b1 = (const float*)d_in[3];
  const float* w2 = (const float*)d_in[4];
  const float* b2 = (const float*)d_in[5];

  char* ws = (char*)d_ws;
  unsigned short* Abuf = (unsigned short*)ws;                 // E*C*M bf16    20,971,520 B
  unsigned short* H    = (unsigned short*)(ws + 20971520);    // E*C*DFF bf16  83,886,080 B
  unsigned short* Wt   = (unsigned short*)(ws + 104857600);   // E*4096*1024 bf16 = 67,108,864 B (reused W1T then W2T)
  int*   slot_token    = (int*)(ws + 171966464);              // E*C int       40,960 B
  int*   eidx          = (int*)(ws + 172007424);              // T int         32,768 B
  float* gate          = (float*)(ws + 172040192);            // T float       32,768 B
  int*   filled        = (int*)(ws + 172072960);              // E int

  // dropped tokens must output zeros; epilogue only writes kept rows
  hipMemsetAsync(d_out, 0, (size_t)out_size * sizeof(float), stream);

  gate_kernel<<<T_TOKENS, 64, 0, stream>>>(x, wg, eidx, gate);
  scan_kernel<<<1, 1024, 0, stream>>>(eidx, slot_token, filled);
  dispatch_kernel<<<NEXP * CAP, 256, 0, stream>>>(x, slot_token, Abuf);

  // W1 [E][M][DFF] fp32 -> Wt [E][DFF][M] bf16
  dim3 gc1(DFF_DIM / 64, MDIM / 64, NEXP);
  transpose_cvt_kernel<MDIM, DFF_DIM><<<gc1, 256, 0, stream>>>(w1, Wt);

  // GEMM1: 256^2 pipelined kernel, 640 blocks (16 colblk * 5 rowblk * 8 e)
  gemm1_256<<<dim3(640), 512, 0, stream>>>(Abuf, Wt, b1, H, filled);

  // W2 [E][DFF][M] fp32 -> Wt [E][M][DFF] bf16 (reuse buffer; stream-ordered after gemm1)
  dim3 gc2(MDIM / 64, DFF_DIM / 64, NEXP);
  transpose_cvt_kernel<DFF_DIM, MDIM><<<gc2, 256, 0, stream>>>(w2, Wt);

  // GEMM2: 640 blocks (8 colblk * 10 rowblk * 8 e), flattened + XCD swizzle
  gemm2_kernel<<<dim3(640), 256, 0, stream>>>(H, Wt, b2, (float*)d_out, slot_token, gate, filled);
}